// Round 1
// baseline (4467.370 us; speedup 1.0000x reference)
//
#include <hip/hip_runtime.h>
#include <hip/hip_bf16.h>
#include <cstdint>
#include <cstddef>

#define NNODES 50000
#define NREL   16
#define DIM    200
#define NEDGE  400000
#define XS_STRIDE 72   // 64 + 8: breaks power-of-2 bank stride, keeps 16B align

// ws layout (bytes):
//  0          : h      float[N*D]   40,000,000
//  40,000,000 : inv    float[R*N]    3,200,000
//  43,200,000 : cnt    int[R*N]      3,200,000
//  46,400,000 : perm   int[E]        1,600,000
//  48,000,000 : hist   int[16]              64
//  48,000,064 : cursor int[16]              64
//  48,000,128 : offs   int[17]              68
// total ~45.8 MiB

__global__ void count_kernel(const int* __restrict__ etype, const int* __restrict__ dst,
                             int* __restrict__ cnt, int* __restrict__ hist) {
    __shared__ int lh[NREL];
    int t = threadIdx.x;
    if (t < NREL) lh[t] = 0;
    __syncthreads();
    int e = blockIdx.x * 256 + t;
    if (e < NEDGE) {
        int r = etype[e];
        atomicAdd(&cnt[r * NNODES + dst[e]], 1);
        atomicAdd(&lh[r], 1);
    }
    __syncthreads();
    if (t < NREL) atomicAdd(&hist[t], lh[t]);
}

__global__ void inv_kernel(const int* __restrict__ cnt, float* __restrict__ inv) {
    int i = blockIdx.x * 256 + threadIdx.x;
    if (i < NREL * NNODES) {
        int c = cnt[i];
        inv[i] = (c > 0) ? 1.0f / (float)c : 0.0f;
    }
}

__global__ void scan_kernel(const int* __restrict__ hist, int* __restrict__ offs) {
    if (threadIdx.x == 0) {
        int s = 0;
        for (int r = 0; r < NREL; ++r) { offs[r] = s; s += hist[r]; }
        offs[NREL] = s;
    }
}

__global__ void scatter_kernel(const int* __restrict__ etype, const int* __restrict__ offs,
                               int* __restrict__ cursor, int* __restrict__ perm) {
    __shared__ int lh[NREL], lbase[NREL], lh2[NREL];
    int t = threadIdx.x;
    if (t < NREL) { lh[t] = 0; lh2[t] = 0; }
    __syncthreads();
    int e = blockIdx.x * 256 + t;
    int r = -1;
    if (e < NEDGE) { r = etype[e]; atomicAdd(&lh[r], 1); }
    __syncthreads();
    if (t < NREL && lh[t] > 0) lbase[t] = atomicAdd(&cursor[t], lh[t]);
    __syncthreads();
    if (e < NEDGE) {
        int p = atomicAdd(&lh2[r], 1);
        perm[offs[r] + lbase[r] + p] = e;
    }
}

// out[v] = bias + x[v] @ Wroot   (direct store, fully writes out)
__global__ __launch_bounds__(256) void root_kernel(
        const float* __restrict__ x, const float* __restrict__ Wroot,
        const float* __restrict__ bias, float* __restrict__ out) {
    __shared__ float xs[DIM * XS_STRIDE];
    int t = threadIdx.x;
    int tc = t & 15, tr = t >> 4;
    for (int vbase = blockIdx.x * 64; vbase < NNODES; vbase += gridDim.x * 64) {
        int cntb = min(64, NNODES - vbase);
        __syncthreads();
        for (int idx = t; idx < 64 * (DIM / 4); idx += 256) {
            int k  = idx / (DIM / 4);
            int d4 = idx - k * (DIM / 4);
            float4 v = make_float4(0.f, 0.f, 0.f, 0.f);
            if (k < cntb) v = *(const float4*)(x + (size_t)(vbase + k) * DIM + d4 * 4);
            int d = d4 * 4;
            xs[(d + 0) * XS_STRIDE + k] = v.x;
            xs[(d + 1) * XS_STRIDE + k] = v.y;
            xs[(d + 2) * XS_STRIDE + k] = v.z;
            xs[(d + 3) * XS_STRIDE + k] = v.w;
        }
        __syncthreads();
        for (int p = 0; p < 4; ++p) {
            int c0 = p * 64 + tc * 4;
            bool cok = (c0 < DIM);
            int ce = cok ? c0 : 0;
            float acc[4][4];
            #pragma unroll
            for (int i = 0; i < 4; ++i)
                #pragma unroll
                for (int j = 0; j < 4; ++j) acc[i][j] = 0.f;
            #pragma unroll 2
            for (int d = 0; d < DIM; ++d) {
                float4 a = *(const float4*)&xs[d * XS_STRIDE + tr * 4];
                float4 w = *(const float4*)(Wroot + d * DIM + ce);
                acc[0][0] += a.x * w.x; acc[0][1] += a.x * w.y; acc[0][2] += a.x * w.z; acc[0][3] += a.x * w.w;
                acc[1][0] += a.y * w.x; acc[1][1] += a.y * w.y; acc[1][2] += a.y * w.z; acc[1][3] += a.y * w.w;
                acc[2][0] += a.z * w.x; acc[2][1] += a.z * w.y; acc[2][2] += a.z * w.z; acc[2][3] += a.z * w.w;
                acc[3][0] += a.w * w.x; acc[3][1] += a.w * w.y; acc[3][2] += a.w * w.z; acc[3][3] += a.w * w.w;
            }
            if (cok) {
                #pragma unroll
                for (int er = 0; er < 4; ++er) {
                    int k = tr * 4 + er;
                    if (k < cntb) {
                        float* o = out + (size_t)(vbase + k) * DIM + c0;
                        o[0] = bias[c0 + 0] + acc[er][0];
                        o[1] = bias[c0 + 1] + acc[er][1];
                        o[2] = bias[c0 + 2] + acc[er][2];
                        o[3] = bias[c0 + 3] + acc[er][3];
                    }
                }
            }
        }
    }
}

// out[dst_e] += w_e * (x[src_e] @ W[r]); blocks grouped by relation via blockIdx.y
__global__ __launch_bounds__(256) void msg_kernel(
        const float* __restrict__ x, const float* __restrict__ W,
        const int* __restrict__ ei, const int* __restrict__ perm,
        const int* __restrict__ offs, const float* __restrict__ inv,
        float* __restrict__ out) {
    __shared__ float xs[DIM * XS_STRIDE];
    __shared__ int s_src[64], s_dst[64];
    __shared__ float s_w[64];
    int t = threadIdx.x;
    int r = blockIdx.y;
    int start = offs[r], end = offs[r + 1];
    const float* Wr = W + (size_t)r * DIM * DIM;
    int tc = t & 15, tr = t >> 4;
    for (int base = start + blockIdx.x * 64; base < end; base += gridDim.x * 64) {
        int cntb = min(64, end - base);
        __syncthreads();   // previous iteration done reading LDS
        if (t < 64) {
            if (t < cntb) {
                int e = perm[base + t];
                int s = ei[e], d = ei[NEDGE + e];
                s_src[t] = s; s_dst[t] = d;
                s_w[t] = inv[r * NNODES + d];
            } else { s_src[t] = 0; s_dst[t] = 0; s_w[t] = 0.0f; }
        }
        __syncthreads();
        for (int idx = t; idx < 64 * (DIM / 4); idx += 256) {
            int k  = idx / (DIM / 4);
            int d4 = idx - k * (DIM / 4);
            float4 v = *(const float4*)(x + (size_t)s_src[k] * DIM + d4 * 4);
            float w = s_w[k];
            int d = d4 * 4;
            xs[(d + 0) * XS_STRIDE + k] = v.x * w;
            xs[(d + 1) * XS_STRIDE + k] = v.y * w;
            xs[(d + 2) * XS_STRIDE + k] = v.z * w;
            xs[(d + 3) * XS_STRIDE + k] = v.w * w;
        }
        __syncthreads();
        for (int p = 0; p < 4; ++p) {
            int c0 = p * 64 + tc * 4;
            bool cok = (c0 < DIM);
            int ce = cok ? c0 : 0;
            float acc[4][4];
            #pragma unroll
            for (int i = 0; i < 4; ++i)
                #pragma unroll
                for (int j = 0; j < 4; ++j) acc[i][j] = 0.f;
            #pragma unroll 2
            for (int d = 0; d < DIM; ++d) {
                float4 a = *(const float4*)&xs[d * XS_STRIDE + tr * 4];
                float4 w = *(const float4*)(Wr + d * DIM + ce);
                acc[0][0] += a.x * w.x; acc[0][1] += a.x * w.y; acc[0][2] += a.x * w.z; acc[0][3] += a.x * w.w;
                acc[1][0] += a.y * w.x; acc[1][1] += a.y * w.y; acc[1][2] += a.y * w.z; acc[1][3] += a.y * w.w;
                acc[2][0] += a.z * w.x; acc[2][1] += a.z * w.y; acc[2][2] += a.z * w.z; acc[2][3] += a.z * w.w;
                acc[3][0] += a.w * w.x; acc[3][1] += a.w * w.y; acc[3][2] += a.w * w.z; acc[3][3] += a.w * w.w;
            }
            if (cok) {
                #pragma unroll
                for (int er = 0; er < 4; ++er) {
                    int e = tr * 4 + er;
                    if (e < cntb) {
                        float* o = out + (size_t)s_dst[e] * DIM + c0;
                        atomicAdd(o + 0, acc[er][0]);
                        atomicAdd(o + 1, acc[er][1]);
                        atomicAdd(o + 2, acc[er][2]);
                        atomicAdd(o + 3, acc[er][3]);
                    }
                }
            }
        }
    }
}

__global__ void relu_kernel(float* __restrict__ h) {
    int n4 = NNODES * DIM / 4;
    for (int i = blockIdx.x * 256 + threadIdx.x; i < n4; i += gridDim.x * 256) {
        float4 v = ((float4*)h)[i];
        v.x = fmaxf(v.x, 0.f); v.y = fmaxf(v.y, 0.f);
        v.z = fmaxf(v.z, 0.f); v.w = fmaxf(v.w, 0.f);
        ((float4*)h)[i] = v;
    }
}

extern "C" void kernel_launch(void* const* d_in, const int* in_sizes, int n_in,
                              void* d_out, int out_size, void* d_ws, size_t ws_size,
                              hipStream_t stream) {
    const int*   edge_index = (const int*)d_in[0];
    const int*   edge_type  = (const int*)d_in[1];
    const float* emb   = (const float*)d_in[2];
    const float* W1    = (const float*)d_in[3];
    const float* root1 = (const float*)d_in[4];
    const float* b1    = (const float*)d_in[5];
    const float* W2    = (const float*)d_in[6];
    const float* root2 = (const float*)d_in[7];
    const float* b2    = (const float*)d_in[8];
    float* out = (float*)d_out;

    char* ws = (char*)d_ws;
    float* h      = (float*)(ws);
    float* inv    = (float*)(ws + 40000000);
    int*   cnt    = (int*)(ws + 43200000);
    int*   perm   = (int*)(ws + 46400000);
    int*   hist   = (int*)(ws + 48000000);
    int*   cursor = (int*)(ws + 48000064);
    int*   offs   = (int*)(ws + 48000128);

    // --- graph preprocessing (re-done every call; ws is re-poisoned) ---
    hipMemsetAsync(cnt, 0, (size_t)NREL * NNODES * sizeof(int), stream);
    hipMemsetAsync(hist, 0, 128, stream);  // hist + cursor
    count_kernel<<<(NEDGE + 255) / 256, 256, 0, stream>>>(edge_type, edge_index + NEDGE, cnt, hist);
    inv_kernel<<<(NREL * NNODES + 255) / 256, 256, 0, stream>>>(cnt, inv);
    scan_kernel<<<1, 64, 0, stream>>>(hist, offs);
    scatter_kernel<<<(NEDGE + 255) / 256, 256, 0, stream>>>(edge_type, offs, cursor, perm);

    // --- layer 1: h = relu(agg(emb,W1) + emb@root1 + b1) ---
    root_kernel<<<782, 256, 0, stream>>>(emb, root1, b1, h);
    msg_kernel<<<dim3(48, NREL), 256, 0, stream>>>(emb, W1, edge_index, perm, offs, inv, h);
    relu_kernel<<<2048, 256, 0, stream>>>(h);

    // --- layer 2: out = agg(h,W2) + h@root2 + b2 ---
    root_kernel<<<782, 256, 0, stream>>>(h, root2, b2, out);
    msg_kernel<<<dim3(48, NREL), 256, 0, stream>>>(h, W2, edge_index, perm, offs, inv, out);
}

// Round 2
// 1622.772 us; speedup vs baseline: 2.7529x; 2.7529x over previous
//
#include <hip/hip_runtime.h>
#include <cstdint>
#include <cstddef>

#define NNODES 50000
#define NREL   16
#define DIM    200
#define NEDGE  400000
#define NKEY   (NREL * NNODES)      // 800000
#define NPART  3125                 // NKEY / 256
#define WTN    208                  // padded n (13 x 16)
#define WTK    224                  // padded k (7 x 32)
#define WTSZ   (17 * WTN * WTK)     // elems per layer's W^T stack

typedef __attribute__((ext_vector_type(8))) short short8;   // 8 bf16
typedef __attribute__((ext_vector_type(4))) float floatx4;  // MFMA C/D

__device__ __forceinline__ unsigned short f2bf(float f) {
    unsigned int u = __float_as_uint(f);
    u = (u + 0x7FFFu + ((u >> 16) & 1u)) >> 16;   // RNE
    return (unsigned short)u;
}
__device__ __forceinline__ float bf2f(unsigned short h) {
    return __uint_as_float(((unsigned int)h) << 16);
}

// ---------- preprocessing: counting sort of edges by key = r*N + dst ----------

__global__ void count_kernel(const int* __restrict__ ei, const int* __restrict__ et,
                             int* __restrict__ cnt) {
    int e = blockIdx.x * 256 + threadIdx.x;
    if (e < NEDGE) atomicAdd(&cnt[et[e] * NNODES + ei[NEDGE + e]], 1);
}

__global__ void scan1_kernel(const int* __restrict__ cnt, int* __restrict__ rp,
                             int* __restrict__ part) {
    __shared__ int sc[256];
    int b = blockIdx.x, t = threadIdx.x, i = b * 256 + t;
    int v = cnt[i];
    sc[t] = v; __syncthreads();
    for (int off = 1; off < 256; off <<= 1) {
        int x = (t >= off) ? sc[t - off] : 0;
        __syncthreads();
        sc[t] += x;
        __syncthreads();
    }
    int incl = sc[t];
    rp[i] = incl - v;                 // block-local exclusive
    if (t == 255) part[b] = incl;     // block total
}

__global__ void scan2_kernel(int* __restrict__ p) {
    __shared__ int sc[256];
    __shared__ int carry_s;
    int t = threadIdx.x;
    if (t == 0) carry_s = 0;
    __syncthreads();
    for (int base = 0; base < NPART; base += 256) {
        int i = base + t;
        int v = (i < NPART) ? p[i] : 0;
        sc[t] = v; __syncthreads();
        for (int off = 1; off < 256; off <<= 1) {
            int x = (t >= off) ? sc[t - off] : 0;
            __syncthreads();
            sc[t] += x;
            __syncthreads();
        }
        int incl = sc[t];
        int carry = carry_s;
        if (i < NPART) p[i] = carry + incl - v;   // exclusive with carry
        __syncthreads();
        if (t == 255) carry_s = carry + incl;
        __syncthreads();
    }
    if (t == 0) p[NPART] = carry_s;   // == NEDGE
}

__global__ void scan3_kernel(int* __restrict__ rp, int* __restrict__ cursor,
                             const int* __restrict__ part) {
    int i = blockIdx.x * 256 + threadIdx.x;
    if (i < NKEY) {
        int v = rp[i] + part[i >> 8];
        rp[i] = v;
        cursor[i] = v;
    } else if (i == NKEY) {
        rp[i] = part[NPART];
    }
}

// perm[pos] = src node of the edge (we never need the edge id itself)
__global__ void scatter_kernel(const int* __restrict__ ei, const int* __restrict__ et,
                               int* __restrict__ cursor, int* __restrict__ perm) {
    int e = blockIdx.x * 256 + threadIdx.x;
    if (e < NEDGE) {
        int key = et[e] * NNODES + ei[NEDGE + e];
        int pos = atomicAdd(&cursor[key], 1);
        perm[pos] = ei[e];
    }
}

// ---------- W^T prep: WT[r][n][k] bf16, zero-padded to 208 x 224; r==16 is root ----------
__global__ void wt_kernel(const float* __restrict__ W, const float* __restrict__ root,
                          unsigned short* __restrict__ WT) {
    int idx = blockIdx.x * 256 + threadIdx.x;
    if (idx >= WTSZ) return;
    int r = idx / (WTN * WTK);
    int rem = idx - r * (WTN * WTK);
    int n = rem / WTK;
    int k = rem - n * WTK;
    float v = 0.f;
    if (n < DIM && k < DIM)
        v = (r < 16) ? W[((size_t)r * DIM + k) * DIM + n] : root[(size_t)k * DIM + n];
    WT[idx] = f2bf(v);
}

// ---------- fused layer: per block, 64 dst rows; 17 K-chunks (16 relations + root) ----------
// As: 64 rows x 400 B (bf16) + 64 B zero slack (k-pad reads hit slack/garbage x B=0)
template<bool SRC_F32, bool OUT_RELU_BF16>
__global__ __launch_bounds__(256) void fused_kernel(
        const void* __restrict__ srcv, const unsigned short* __restrict__ WT,
        const int* __restrict__ rp, const int* __restrict__ perm,
        const float* __restrict__ bias, void* __restrict__ outv) {
    __shared__ __align__(16) char As[25664];
    const int t = threadIdx.x;
    const int w = t >> 6;          // wave 0..3 -> m-rows [w*16, w*16+16)
    const int lane = t & 63;
    const int quad = lane >> 4;
    const int mn = lane & 15;
    const int v0 = blockIdx.x * 64;

    if (t < 16) *(unsigned int*)(As + 25600 + t * 4) = 0u;  // zero slack once

    floatx4 acc[13];
    #pragma unroll
    for (int i = 0; i < 13; ++i) acc[i] = (floatx4){0.f, 0.f, 0.f, 0.f};

    const float* srcf = (const float*)srcv;
    const unsigned short* srcb = (const unsigned short*)srcv;

    for (int r = 0; r < 17; ++r) {
        __syncthreads();   // previous chunk's MFMA done reading As
        // ---- build A-tile: wave w builds its 16 rows (gather + mean, bf16) ----
        for (int i = 0; i < 16; ++i) {
            const int m = w * 16 + i;
            const int v = v0 + m;
            float a0 = 0.f, a1 = 0.f, a2 = 0.f, a3 = 0.f;
            if (v < NNODES) {
                if (r < 16) {
                    const int key = r * NNODES + v;
                    const int s = rp[key], e = rp[key + 1];
                    for (int j = s; j < e; ++j) {
                        const int sv = perm[j];
                        if (lane < 50) {
                            if (SRC_F32) {
                                const float4 q = *(const float4*)(srcf + (size_t)sv * DIM + lane * 4);
                                a0 += q.x; a1 += q.y; a2 += q.z; a3 += q.w;
                            } else {
                                const ushort4 q = *(const ushort4*)(srcb + (size_t)sv * DIM + lane * 4);
                                a0 += bf2f(q.x); a1 += bf2f(q.y); a2 += bf2f(q.z); a3 += bf2f(q.w);
                            }
                        }
                    }
                    const float sc = (e > s) ? 1.f / (float)(e - s) : 0.f;
                    a0 *= sc; a1 *= sc; a2 *= sc; a3 *= sc;
                } else {   // root chunk: A = x itself
                    if (lane < 50) {
                        if (SRC_F32) {
                            const float4 q = *(const float4*)(srcf + (size_t)v * DIM + lane * 4);
                            a0 = q.x; a1 = q.y; a2 = q.z; a3 = q.w;
                        } else {
                            const ushort4 q = *(const ushort4*)(srcb + (size_t)v * DIM + lane * 4);
                            a0 = bf2f(q.x); a1 = bf2f(q.y); a2 = bf2f(q.z); a3 = bf2f(q.w);
                        }
                    }
                }
            }
            if (lane < 50) {
                ushort4 pk;
                pk.x = f2bf(a0); pk.y = f2bf(a1); pk.z = f2bf(a2); pk.w = f2bf(a3);
                *(ushort4*)(As + m * 400 + lane * 8) = pk;
            }
        }
        __syncthreads();   // As ready
        // ---- MFMA: C[64x208] += As[64x200(+pad)] @ WT_r ----
        // A-frag: A[m = lane&15][k = quad*8 + j]   B-frag: B[k = quad*8 + j][n = lane&15]
        const char* WTr = (const char*)(WT + (size_t)r * (WTN * WTK));
        const char* arow = As + (w * 16 + mn) * 400 + quad * 16;
        const char* brow = WTr + (size_t)mn * (WTK * 2) + quad * 16;
        for (int ks = 0; ks < 7; ++ks) {
            const short8 af = *(const short8*)(arow + ks * 64);
            #pragma unroll
            for (int nt = 0; nt < 13; ++nt) {
                const short8 bf = *(const short8*)(brow + ks * 64 + nt * (16 * WTK * 2));
                acc[nt] = __builtin_amdgcn_mfma_f32_16x16x32_bf16(af, bf, acc[nt], 0, 0, 0);
            }
        }
    }

    // ---- epilogue: C row = quad*4 + i (within wave's 16), col = nt*16 + mn ----
    float* outf = (float*)outv;
    unsigned short* outb = (unsigned short*)outv;
    #pragma unroll
    for (int nt = 0; nt < 13; ++nt) {
        const int col = nt * 16 + mn;
        if (col < DIM) {
            const float bv = bias[col];
            #pragma unroll
            for (int i = 0; i < 4; ++i) {
                const int v = v0 + w * 16 + quad * 4 + i;
                if (v < NNODES) {
                    float x = acc[nt][i] + bv;
                    if (OUT_RELU_BF16) {
                        x = fmaxf(x, 0.f);
                        outb[(size_t)v * DIM + col] = f2bf(x);
                    } else {
                        outf[(size_t)v * DIM + col] = x;
                    }
                }
            }
        }
    }
}

// ---------- launch ----------

extern "C" void kernel_launch(void* const* d_in, const int* in_sizes, int n_in,
                              void* d_out, int out_size, void* d_ws, size_t ws_size,
                              hipStream_t stream) {
    const int*   edge_index = (const int*)d_in[0];
    const int*   edge_type  = (const int*)d_in[1];
    const float* emb   = (const float*)d_in[2];
    const float* W1    = (const float*)d_in[3];
    const float* root1 = (const float*)d_in[4];
    const float* b1    = (const float*)d_in[5];
    const float* W2    = (const float*)d_in[6];
    const float* root2 = (const float*)d_in[7];
    const float* b2    = (const float*)d_in[8];
    float* out = (float*)d_out;

    // ws layout (bytes):
    //  cnt    0           3,200,000
    //  rp     3,200,000   3,200,128  (800001 ints, padded)
    //  cursor 6,400,128   3,200,000
    //  part   9,600,128      12,544  (3126 ints, padded)
    //  perm   9,612,672   1,600,000
    //  hbf   11,212,672  20,000,000  (bf16 h, layer-1 output)
    //  WT1   31,212,672   1,584,128
    //  WT2   32,796,800   1,584,128
    char* ws = (char*)d_ws;
    int*            cnt    = (int*)(ws);
    int*            rp     = (int*)(ws + 3200000);
    int*            cursor = (int*)(ws + 6400128);
    int*            part   = (int*)(ws + 9600128);
    int*            perm   = (int*)(ws + 9612672);
    unsigned short* hbf    = (unsigned short*)(ws + 11212672);
    unsigned short* WT1    = (unsigned short*)(ws + 31212672);
    unsigned short* WT2    = (unsigned short*)(ws + 32796800);

    // counting sort by key = r*N + dst
    hipMemsetAsync(cnt, 0, (size_t)NKEY * sizeof(int), stream);
    count_kernel<<<(NEDGE + 255) / 256, 256, 0, stream>>>(edge_index, edge_type, cnt);
    scan1_kernel<<<NPART, 256, 0, stream>>>(cnt, rp, part);
    scan2_kernel<<<1, 256, 0, stream>>>(part);
    scan3_kernel<<<(NKEY + 256) / 256 + 1, 256, 0, stream>>>(rp, cursor, part);
    scatter_kernel<<<(NEDGE + 255) / 256, 256, 0, stream>>>(edge_index, edge_type, cursor, perm);

    // W^T (bf16, padded) for both layers
    wt_kernel<<<(WTSZ + 255) / 256, 256, 0, stream>>>(W1, root1, WT1);
    wt_kernel<<<(WTSZ + 255) / 256, 256, 0, stream>>>(W2, root2, WT2);

    const int nblk = (NNODES + 63) / 64;   // 782
    // layer 1: h = relu(agg(emb) + emb@root1 + b1) -> bf16
    fused_kernel<true, true><<<nblk, 256, 0, stream>>>(emb, WT1, rp, perm, b1, hbf);
    // layer 2: out = agg(h) + h@root2 + b2 -> fp32
    fused_kernel<false, false><<<nblk, 256, 0, stream>>>(hbf, WT2, rp, perm, b2, out);
}